// Round 9
// baseline (231.929 us; speedup 1.0000x reference)
//
#include <hip/hip_runtime.h>
#include <hip/hip_bf16.h>

#define N_NODES   51200
#define N_GRAPHS  64
#define N_EDGES   819200
#define DIM_IN    128
#define DH        64
#define HEADS     3
#define DIM_OUT   64
#define CAP       96       // bucket capacity per dst node (R6-proven); P(deg>96) ~ 0
#define NPART     64       // scatter partitions: 800 nodes each (pure node-space split)
#define PART_SZ   800
#define BIN_BLOCKS  400    // N_EDGES / 2048
#define SEG_CAP   80       // per-(bin-block,partition) segment cap; P(Binom(2048,1/64)>=80) ~ 1e-17
#define PREP_BLOCKS 116    // 29696 weight-prep elements / 256
#define SC_BLOCKS   NPART  // 64 counting-scatter blocks
#define K1_BLOCKS   (N_NODES / 64)   // 800

typedef __hip_bfloat16 bf16;
typedef short bf16x8 __attribute__((ext_vector_type(8)));
typedef float f32x4  __attribute__((ext_vector_type(4)));

__device__ __forceinline__ float b2f(bf16 x) { return __bfloat162float(x); }
__device__ __forceinline__ bf16  f2b(float x) { return __float2bfloat16(x); }
__device__ __forceinline__ short f2bs(float x) { return (short)__bfloat16_as_ushort(f2b(x)); }
__device__ __forceinline__ float leaky(float x, float s) { return x >= 0.f ? x : s * x; }
// flag-branched input load: f32==1 -> data is float32 (the ACTIVE path per earlier bisect)
__device__ __forceinline__ float ldin(const void* p, size_t i, int f32) {
    return f32 ? ((const float*)p)[i] : b2f(((const bf16*)p)[i]);
}
__device__ __forceinline__ bf16x8 ld8(const void* p, size_t i, int f32) {
    if (!f32) return *((const bf16x8*)((const short*)p + i));
    const float* f = (const float*)p + i;
    bf16x8 r;
    #pragma unroll
    for (int j = 0; j < 8; ++j) r[j] = f2bs(f[j]);
    return r;
}

// ---------- pass A: segment-binning (no init needed: bcnt fully rewritten each replay)
// + weight prep + detect. pbuf[part][binblk][SEG_CAP] u32 = (src<<16)|dlocal.
__global__ __launch_bounds__(256) void k_bin_prep(const int* __restrict__ src,
                                                  const int* __restrict__ dst,
                                                  unsigned* __restrict__ pbuf,
                                                  int* __restrict__ bcnt,   // [part][binblk]
                                                  const void* __restrict__ X,
                                                  const void* __restrict__ W1,
                                                  const void* __restrict__ Wsrc,
                                                  const void* __restrict__ Wdst,
                                                  const void* __restrict__ Wf,
                                                  const void* __restrict__ att_src,
                                                  const void* __restrict__ att_dst,
                                                  int* __restrict__ flag,
                                                  short* __restrict__ W1t,
                                                  short* __restrict__ Wspt,
                                                  short* __restrict__ Wft,
                                                  short* __restrict__ Wat) {
    const int tid = threadIdx.x;
    if (blockIdx.x < BIN_BLOCKS) {
        __shared__ int cnt[NPART];
        const int b = blockIdx.x;
        if (tid < NPART) cnt[tid] = 0;
        __syncthreads();
        const int e0 = b * 2048;
        #pragma unroll
        for (int t = 0; t < 8; ++t) {
            int e = e0 + t * 256 + tid;
            int s = src[e], d = dst[e];
            int p = d / PART_SZ;
            int dl = d - p * PART_SZ;
            int r = atomicAdd(&cnt[p], 1);
            if (r < SEG_CAP)
                pbuf[((size_t)p * BIN_BLOCKS + b) * SEG_CAP + r] =
                    ((unsigned)s << 16) | (unsigned)dl;
        }
        __syncthreads();
        if (tid < NPART) bcnt[tid * BIN_BLOCKS + b] = min(cnt[tid], SEG_CAP);
        return;
    }
    if (blockIdx.x < BIN_BLOCKS + PREP_BLOCKS) {
        // self-probe dtype (R5-validated): 256-sample exponent test on X
        unsigned ex = (((const unsigned short*)X)[2 * tid] >> 7) & 0xFF;
        int c = __syncthreads_count(ex >= 110 && ex <= 135);
        const int f32 = (c < 128) ? 1 : 0;
        int idx = (blockIdx.x - BIN_BLOCKS) * 256 + tid;
        if (idx < 8192) {
            int n = idx >> 7, k = idx & 127;
            W1t[idx] = f2bs(ldin(W1, (size_t)k * 64 + n, f32));
        } else if (idx < 20480) {
            int j = idx - 8192;
            int col = j / 192;
            int rem = j - col * 192;           // rem = h*64 + kk
            int hh = rem >> 6, kk = rem & 63;
            Wspt[j] = f2bs(ldin(Wsrc, (size_t)kk * 192 + hh * 64 + col, f32) * (1.0f / 3.0f));
        } else if (idx < 28672) {
            int j = idx - 20480;
            int n = j >> 7, k = j & 127;
            Wft[j] = f2bs(ldin(Wf, (size_t)k * 64 + n, f32));
        } else if (idx < 29696) {
            int j = idx - 28672;
            int n = j >> 6, k = j & 63;
            float v = 0.f;
            if (n < 3) {
                for (int c2 = 0; c2 < 64; ++c2)
                    v += ldin(Wsrc, (size_t)k * 192 + n * 64 + c2, f32) * ldin(att_src, n * 64 + c2, f32);
            } else if (n < 6) {
                for (int c2 = 0; c2 < 64; ++c2)
                    v += ldin(Wdst, (size_t)k * 192 + (n - 3) * 64 + c2, f32) * ldin(att_dst, (n - 3) * 64 + c2, f32);
            }
            Wat[j] = f2bs(v);
        }
        return;
    }
    // detect block: write the global flag consumed by downstream kernels
    __shared__ int cntp;
    if (tid == 0) cntp = 0;
    __syncthreads();
    int local = 0;
    const unsigned short* Xu = (const unsigned short*)X;
    for (int i = tid * 2; i < 8192; i += 512) {
        unsigned e = (Xu[i] >> 7) & 0xFF;
        if (e >= 110 && e <= 135) local++;
    }
    atomicAdd(&cntp, local);
    __syncthreads();
    if (tid == 0) *flag = (cntp < 2048) ? 1 : 0;  // 1 = fp32, 0 = bf16
}

// ---------- pass B: LDS counting scatter (64 blocks, zero global atomics) || k1 (800 blocks).
// Scatter block p walks its 400 segments (slot-parallel), buckets src u16 entries by dst
// with LDS counters, writes cursor coalesced. k1 co-resides and hides the latency.
__global__ __launch_bounds__(256) void k_scatter_k1(const unsigned* __restrict__ pbuf,
                                                    const int* __restrict__ bcnt,
                                                    int* __restrict__ cursor,
                                                    unsigned short* __restrict__ bucket,
                                                    const void* __restrict__ X,
                                                    const short* __restrict__ W1t,
                                                    const short* __restrict__ Wat,
                                                    const void* __restrict__ b1,
                                                    const int* __restrict__ flagp,
                                                    bf16* __restrict__ h_bf,
                                                    unsigned char* __restrict__ h8,
                                                    float* __restrict__ a_src4,
                                                    float* __restrict__ a_dst4) {
    __shared__ short hs[64 * 72];       // k1 tile
    __shared__ int cnt2[PART_SZ];       // scatter branch: per-node counters (3.2KB)
    __shared__ int bc[BIN_BLOCKS];      // scatter branch: segment counts (1.6KB)
    const int tid = threadIdx.x;
    if (blockIdx.x < SC_BLOCKS) {
        const int p = blockIdx.x;
        const int nbase = p * PART_SZ;
        for (int i = tid; i < PART_SZ; i += 256) cnt2[i] = 0;
        for (int i = tid; i < BIN_BLOCKS; i += 256) bc[i] = bcnt[p * BIN_BLOCKS + i];
        __syncthreads();
        const unsigned* pb = pbuf + (size_t)p * BIN_BLOCKS * SEG_CAP;
        for (int i = tid; i < BIN_BLOCKS * SEG_CAP; i += 256) {
            int b = (unsigned)i / SEG_CAP;
            int r = i - b * SEG_CAP;
            if (r < bc[b]) {
                unsigned pk = pb[i];
                int dl = (int)(pk & 0xFFFFu);
                int pos = atomicAdd(&cnt2[dl], 1);
                if (pos < CAP) bucket[(size_t)(nbase + dl) * CAP + pos] = (unsigned short)(pk >> 16);
            }
        }
        __syncthreads();
        for (int i = tid; i < PART_SZ; i += 256) cursor[nbase + i] = cnt2[i];
        return;
    }
    // ----- k1 branch -----
    const int f32 = *flagp;
    const int w    = tid >> 6;
    const int lane = tid & 63;
    const int lm   = lane & 15;
    const int q    = lane >> 4;
    const int row0 = (blockIdx.x - SC_BLOCKS) * 64;

    const float bias = ldin(b1, w * 16 + lm, f32);
    for (int mt = 0; mt < 4; ++mt) {
        f32x4 acc = {0.f, 0.f, 0.f, 0.f};
        #pragma unroll
        for (int kc = 0; kc < 4; ++kc) {
            bf16x8 a = ld8(X, (size_t)(row0 + mt * 16 + lm) * 128 + kc * 32 + q * 8, f32);
            bf16x8 b = *((const bf16x8*)(W1t + (size_t)(w * 16 + lm) * 128 + kc * 32 + q * 8));
            acc = __builtin_amdgcn_mfma_f32_16x16x32_bf16(a, b, acc, 0, 0, 0);
        }
        #pragma unroll
        for (int r = 0; r < 4; ++r) {
            int row = mt * 16 + q * 4 + r;
            float v = leaky(acc[r] + bias, 0.01f);
            short hv = f2bs(v);
            hs[row * 72 + w * 16 + lm] = hv;
            h_bf[(size_t)(row0 + row) * 64 + w * 16 + lm] = __ushort_as_bfloat16((unsigned short)hv);
            h8[(size_t)(row0 + row) * 64 + w * 16 + lm] =
                (unsigned char)__builtin_amdgcn_cvt_pk_fp8_f32(v, 0.f, 0, false);
        }
    }
    __syncthreads();
    {   // stage2: attention-logit projection, wave w owns row-tile mt=w
        const int mt = w;
        bf16x8 a0  = *((const bf16x8*)(hs + (mt * 16 + lm) * 72 + q * 8));
        bf16x8 a1  = *((const bf16x8*)(hs + (mt * 16 + lm) * 72 + 32 + q * 8));
        bf16x8 b0  = *((const bf16x8*)(Wat + (size_t)lm * 64 + q * 8));
        bf16x8 b1v = *((const bf16x8*)(Wat + (size_t)lm * 64 + 32 + q * 8));
        f32x4 acca = {0.f, 0.f, 0.f, 0.f};
        acca = __builtin_amdgcn_mfma_f32_16x16x32_bf16(a0, b0, acca, 0, 0, 0);
        acca = __builtin_amdgcn_mfma_f32_16x16x32_bf16(a1, b1v, acca, 0, 0, 0);
        if (lm < 6) {
            #pragma unroll
            for (int r = 0; r < 4; ++r) {
                int row = row0 + mt * 16 + q * 4 + r;
                if (lm < 3) a_src4[(size_t)row * 4 + lm] = acca[r];
                else        a_dst4[(size_t)row * 4 + (lm - 3)] = acca[r];
            }
        }
    }
}

// ---------- edge aggregation (R6-proven): wave per dst node; fp8 h gather (64B/edge).
__global__ __launch_bounds__(256) void edge_kernel(const unsigned short* __restrict__ bucket,
                                                   const int* __restrict__ cursor,
                                                   const float* __restrict__ a_src4,
                                                   const float* __restrict__ a_dst4,
                                                   const unsigned char* __restrict__ h8,
                                                   float4* __restrict__ dstinfo,
                                                   bf16* __restrict__ wagg) {
    const int lane = threadIdx.x & 63;
    const int w = threadIdx.x >> 6;
    const int n = blockIdx.x * 4 + w;
    const int dg = min(cursor[n], CAP);
    const float4 ad = ((const float4*)a_dst4)[n];
    __shared__ float4 buf[4][64];
    float den0 = 0.f, den1 = 0.f, den2 = 0.f;   // producer-side partials
    float acc0 = 0.f, acc1 = 0.f, acc2 = 0.f;
    for (int c0 = 0; c0 < dg; c0 += 64) {
        int cnt = min(64, dg - c0);
        if (lane < cnt) {
            int s = bucket[(size_t)n * CAP + c0 + lane];
            const float4 as = ((const float4*)a_src4)[s];
            float e0 = __expf(leaky(as.x + ad.x, 0.2f));
            float e1 = __expf(leaky(as.y + ad.y, 0.2f));
            float e2 = __expf(leaky(as.z + ad.z, 0.2f));
            den0 += e0; den1 += e1; den2 += e2;
            buf[w][lane] = make_float4(e0, e1, e2, __int_as_float(s));
        }
        asm volatile("s_waitcnt lgkmcnt(0)" ::: "memory");
        int j = 0;
        for (; j + 8 <= cnt; j += 8) {
            float4 r[8]; int hv[8];
            #pragma unroll
            for (int u = 0; u < 8; ++u) r[u] = buf[w][j + u];
            #pragma unroll
            for (int u = 0; u < 8; ++u)
                hv[u] = (int)h8[(((unsigned)__float_as_int(r[u].w)) << 6) | (unsigned)lane];
            #pragma unroll
            for (int u = 0; u < 8; ++u) {
                float f = __builtin_amdgcn_cvt_f32_fp8(hv[u], 0);
                acc0 += r[u].x * f; acc1 += r[u].y * f; acc2 += r[u].z * f;
            }
        }
        for (; j < cnt; ++j) {
            float4 r = buf[w][j];
            int hvv = (int)h8[(((unsigned)__float_as_int(r.w)) << 6) | (unsigned)lane];
            float f = __builtin_amdgcn_cvt_f32_fp8(hvv, 0);
            acc0 += r.x * f; acc1 += r.y * f; acc2 += r.z * f;
        }
    }
    #pragma unroll
    for (int off = 32; off >= 1; off >>= 1) {
        den0 += __shfl_xor(den0, off);
        den1 += __shfl_xor(den1, off);
        den2 += __shfl_xor(den2, off);
    }
    float inv0 = den0 > 0.f ? 1.f / den0 : 0.f;
    float inv1 = den1 > 0.f ? 1.f / den1 : 0.f;
    float inv2 = den2 > 0.f ? 1.f / den2 : 0.f;
    size_t wb = (size_t)n * 192;
    wagg[wb + lane]       = f2b(acc0 * inv0);
    wagg[wb + 64 + lane]  = f2b(acc1 * inv1);
    wagg[wb + 128 + lane] = f2b(acc2 * inv2);
    if (lane == 0) {
        dstinfo[(size_t)n * 2 + 0] = make_float4(ad.x, ad.y, ad.z, 0.f);
        dstinfo[(size_t)n * 2 + 1] = make_float4(inv0, inv1, inv2, 0.f);
    }
}

// ---------- fused attn (edge-order, blocks 0..3199) + g3 (blocks 3200..3999) with pool fold.
// (R6-proven form: psum/done zeroed by host-side memset each launch.)
__global__ __launch_bounds__(256) void attn_g3_kernel(const int* __restrict__ src,
                                                      const int* __restrict__ dst,
                                                      const float* __restrict__ a_src4,
                                                      const float4* __restrict__ dstinfo,
                                                      const bf16* __restrict__ h_bf,
                                                      const bf16* __restrict__ wagg,
                                                      const short* __restrict__ Wspt,
                                                      const short* __restrict__ Wft,
                                                      const void* __restrict__ gat_bias,
                                                      const void* __restrict__ bfv,
                                                      const int* __restrict__ flagp,
                                                      const int* __restrict__ gptr,
                                                      float* __restrict__ psum,
                                                      int* __restrict__ done,
                                                      void* __restrict__ d_out) {
    const int f32 = *flagp;
    __shared__ short cs[64 * 136];           // g3 branch only
    __shared__ int sptr[N_GRAPHS + 1];
    __shared__ int rowg_s[64];
    __shared__ int readyg[64];
    __shared__ int nready;
    if (blockIdx.x < N_EDGES / 256) {
        int e = blockIdx.x * 256 + threadIdx.x;
        int s = src[e], d = dst[e];
        const float4 as = ((const float4*)a_src4)[s];
        const float4 ad = dstinfo[(size_t)d * 2 + 0];
        const float4 cv = dstinfo[(size_t)d * 2 + 1];
        float a0 = __expf(leaky(as.x + ad.x, 0.2f)) * cv.x;
        float a1 = __expf(leaky(as.y + ad.y, 0.2f)) * cv.y;
        float a2 = __expf(leaky(as.z + ad.z, 0.2f)) * cv.z;
        size_t o = (size_t)N_GRAPHS * DIM_OUT + (size_t)e * 3;
        if (f32) {
            float* p = (float*)d_out;
            p[o] = a0; p[o + 1] = a1; p[o + 2] = a2;
        } else {
            bf16* p = (bf16*)d_out;
            p[o] = f2b(a0); p[o + 1] = f2b(a1); p[o + 2] = f2b(a2);
        }
        return;
    }
    const int bid  = blockIdx.x - N_EDGES / 256;
    const int tid  = threadIdx.x;
    const int w    = tid >> 6;
    const int lane = tid & 63;
    const int lm   = lane & 15;
    const int q    = lane >> 4;
    const int row0 = bid * 64;
    if (tid <= N_GRAPHS) sptr[tid] = gptr[tid];
    if (tid == 0) nready = 0;
    __syncthreads();
    if (tid < 64) {   // row -> graph (binary search; general ptr)
        int row = row0 + tid;
        int lo2 = 0, hi2 = N_GRAPHS;
        while (hi2 - lo2 > 1) { int mid = (lo2 + hi2) >> 1; if (sptr[mid] <= row) lo2 = mid; else hi2 = mid; }
        rowg_s[tid] = lo2;
    }
    // cat[:, 0:64] = leaky(h)
    for (int idx = tid; idx < 64 * 64; idx += 256) {
        int r = idx >> 6, k = idx & 63;
        cs[r * 136 + k] = f2bs(leaky(b2f(h_bf[(size_t)(row0 + r) * 64 + k]), 0.01f));
    }
    // cat[:, 64:128] = leaky(mean_h(wagg_h @ Wsrc_h) + gat_bias)
    {
        const int col = w * 16 + lm;
        const float gb = ldin(gat_bias, col, f32);
        for (int mt = 0; mt < 4; ++mt) {
            f32x4 acc = {0.f, 0.f, 0.f, 0.f};
            #pragma unroll
            for (int kc = 0; kc < 6; ++kc) {
                bf16x8 a = *((const bf16x8*)((const short*)wagg + (size_t)(row0 + mt * 16 + lm) * 192 + kc * 32 + q * 8));
                bf16x8 b = *((const bf16x8*)(Wspt + (size_t)col * 192 + kc * 32 + q * 8));
                acc = __builtin_amdgcn_mfma_f32_16x16x32_bf16(a, b, acc, 0, 0, 0);
            }
            #pragma unroll
            for (int r = 0; r < 4; ++r) {
                int row = mt * 16 + q * 4 + r;
                cs[row * 136 + 64 + col] = f2bs(leaky(acc[r] + gb, 0.01f));
            }
        }
    }
    __syncthreads();
    // final GEMM: y = cat @ Wf + bf, reduced straight into per-graph psum (no y write)
    {
        const int col = w * 16 + lm;
        const float bias = ldin(bfv, col, f32);
        int curg = -1; float runsum = 0.f;
        for (int mt = 0; mt < 4; ++mt) {
            f32x4 acc = {0.f, 0.f, 0.f, 0.f};
            #pragma unroll
            for (int kc = 0; kc < 4; ++kc) {
                bf16x8 a = *((const bf16x8*)(cs + (mt * 16 + lm) * 136 + kc * 32 + q * 8));
                bf16x8 b = *((const bf16x8*)(Wft + (size_t)col * 128 + kc * 32 + q * 8));
                acc = __builtin_amdgcn_mfma_f32_16x16x32_bf16(a, b, acc, 0, 0, 0);
            }
            #pragma unroll
            for (int r = 0; r < 4; ++r) {
                int lrow = mt * 16 + q * 4 + r;
                float v = acc[r] + bias;
                int g = rowg_s[lrow];
                if (g != curg) {
                    if (curg >= 0) atomicAdd(&psum[curg * 64 + col], runsum);
                    curg = g; runsum = 0.f;
                }
                runsum += v;
            }
        }
        if (curg >= 0) atomicAdd(&psum[curg * 64 + col], runsum);
    }
    __syncthreads();   // barrier drains vmcnt -> this block's psum adds are at the coherence point
    if (tid == 0) {
        int g0 = rowg_s[0], g1 = rowg_s[63];
        int nr = 0;
        for (int g = g0; g <= g1; ++g) {
            int lo = sptr[g], hi = sptr[g + 1];
            if (hi <= lo) continue;                       // empty graph
            int expected = (hi - 1) / 64 - lo / 64 + 1;   // tiles overlapping graph g
            int old = atomicAdd(&done[g], 1);
            if (old == expected - 1) readyg[nr++] = g;    // this block is the last tile of g
        }
        nready = nr;
    }
    __syncthreads();
    for (int i = 0; i < nready; ++i) {
        int g = readyg[i];
        if (tid < 64) {
            float s = atomicAdd(&psum[g * 64 + tid], 0.0f);    // coherent read at LLC
            float v = s / (float)(sptr[g + 1] - sptr[g]);
            if (f32) ((float*)d_out)[g * DIM_OUT + tid] = v;
            else     ((bf16*)d_out)[g * DIM_OUT + tid]  = f2b(v);
        }
    }
}

extern "C" void kernel_launch(void* const* d_in, const int* in_sizes, int n_in,
                              void* d_out, int out_size, void* d_ws, size_t ws_size,
                              hipStream_t stream) {
    const void* X        = d_in[0];
    const void* W1       = d_in[1];
    const void* b1       = d_in[2];
    const void* Wsrc     = d_in[3];
    const void* Wdst     = d_in[4];
    const void* att_src  = d_in[5];
    const void* att_dst  = d_in[6];
    const void* gat_bias = d_in[7];
    const void* Wf       = d_in[8];
    const void* bfv      = d_in[9];
    const int*  ei       = (const int*)d_in[10];
    const int*  ptr      = (const int*)d_in[11];
    const int*  src  = ei;
    const int*  dstp = ei + N_EDGES;

    char* ws = (char*)d_ws;
    size_t off_b = 0;
    auto alloc = [&](size_t bytes) -> char* {
        char* p = ws + off_b;
        off_b += (bytes + 255) & ~(size_t)255;
        return p;
    };
    int*     flag    = (int*)    alloc(256);
    short*   W1t     = (short*)  alloc(8192 * 2);
    short*   Wspt    = (short*)  alloc(12288 * 2);
    short*   Wft     = (short*)  alloc(8192 * 2);
    short*   Wat     = (short*)  alloc(1024 * 2);
    bf16*    h_bf    = (bf16*)   alloc((size_t)N_NODES * 64 * 2);
    unsigned char* h8 = (unsigned char*)alloc((size_t)N_NODES * 64);
    float*   a_src4  = (float*)  alloc((size_t)N_NODES * 16);
    float*   a_dst4  = (float*)  alloc((size_t)N_NODES * 16);
    float4*  dstinfo = (float4*) alloc((size_t)N_NODES * 2 * 16);
    bf16*    wagg    = (bf16*)   alloc((size_t)N_NODES * 192 * 2);
    // zeroed region (one small memset): psum(16KB) + done(256B)
    float*   psum    = (float*)  alloc((size_t)N_GRAPHS * 64 * 4);
    int*     done    = (int*)    alloc(256);
    int*     bcnt    = (int*)    alloc((size_t)NPART * BIN_BLOCKS * 4);  // fully rewritten each replay
    int*     cursor  = (int*)    alloc((size_t)N_NODES * 4);             // fully rewritten each replay
    unsigned short* bucket = (unsigned short*)alloc((size_t)N_NODES * CAP * 2);  // 9.8MB
    unsigned* pbuf   = (unsigned*)wagg;    // alias: pbuf (8.2MB) dead before edge_kernel writes wagg
    if (off_b > ws_size) return;

    hipMemsetAsync(psum, 0, (size_t)N_GRAPHS * 64 * 4 + 256, stream);   // psum + done (adjacent)
    hipLaunchKernelGGL(k_bin_prep, dim3(BIN_BLOCKS + PREP_BLOCKS + 1), dim3(256), 0, stream,
                       src, dstp, pbuf, bcnt,
                       X, W1, Wsrc, Wdst, Wf, att_src, att_dst, flag, W1t, Wspt, Wft, Wat);
    hipLaunchKernelGGL(k_scatter_k1, dim3(SC_BLOCKS + K1_BLOCKS), dim3(256), 0, stream,
                       pbuf, bcnt, cursor, bucket,
                       X, W1t, Wat, b1, flag, h_bf, h8, a_src4, a_dst4);
    hipLaunchKernelGGL(edge_kernel, dim3(N_NODES / 4), dim3(256), 0, stream,
                       bucket, cursor, a_src4, a_dst4, h8, dstinfo, wagg);
    hipLaunchKernelGGL(attn_g3_kernel, dim3(N_EDGES / 256 + N_NODES / 64), dim3(256), 0, stream,
                       src, dstp, a_src4, dstinfo, h_bf, wagg, Wspt, Wft,
                       gat_bias, bfv, flag, ptr, psum, done, d_out);
}

// Round 11
// 210.317 us; speedup vs baseline: 1.1028x; 1.1028x over previous
//
#include <hip/hip_runtime.h>
#include <hip/hip_bf16.h>

#define N_NODES   51200
#define N_GRAPHS  64
#define N_EDGES   819200
#define DIM_IN    128
#define DH        64
#define HEADS     3
#define DIM_OUT   64
#define CAP       96       // bucket capacity per dst node (R6-proven); P(deg>96) ~ 0
#define NPART     256      // scatter partitions: 200 nodes each (pure node-space split)
#define PART_SZ   200
#define BIN_BLOCKS  400    // N_EDGES / 2048
#define SEG_CAP   36       // per-(bin-block,partition) cap; P(Poisson(8)>=36) ~ 1e-31
#define PREP_BLOCKS 116    // 29696 weight-prep elements / 256
#define SC_BLOCKS   NPART  // 256 counting-scatter blocks
#define K1_BLOCKS   (N_NODES / 64)   // 800

typedef __hip_bfloat16 bf16;
typedef short bf16x8 __attribute__((ext_vector_type(8)));
typedef float f32x4  __attribute__((ext_vector_type(4)));

__device__ __forceinline__ float b2f(bf16 x) { return __bfloat162float(x); }
__device__ __forceinline__ bf16  f2b(float x) { return __float2bfloat16(x); }
__device__ __forceinline__ short f2bs(float x) { return (short)__bfloat16_as_ushort(f2b(x)); }
__device__ __forceinline__ float leaky(float x, float s) { return x >= 0.f ? x : s * x; }
// flag-branched input load: f32==1 -> data is float32 (the ACTIVE path per earlier bisect)
__device__ __forceinline__ float ldin(const void* p, size_t i, int f32) {
    return f32 ? ((const float*)p)[i] : b2f(((const bf16*)p)[i]);
}
__device__ __forceinline__ bf16x8 ld8(const void* p, size_t i, int f32) {
    if (!f32) return *((const bf16x8*)((const short*)p + i));
    const float* f = (const float*)p + i;
    bf16x8 r;
    #pragma unroll
    for (int j = 0; j < 8; ++j) r[j] = f2bs(f[j]);
    return r;
}

// ---------- pass A: segment-binning (no init needed: bcnt fully rewritten each replay)
// + weight prep + detect. pbuf[part][binblk][SEG_CAP] u32 = (src<<16)|dlocal.
__global__ __launch_bounds__(256) void k_bin_prep(const int* __restrict__ src,
                                                  const int* __restrict__ dst,
                                                  unsigned* __restrict__ pbuf,
                                                  int* __restrict__ bcnt,   // [part][binblk]
                                                  const void* __restrict__ X,
                                                  const void* __restrict__ W1,
                                                  const void* __restrict__ Wsrc,
                                                  const void* __restrict__ Wdst,
                                                  const void* __restrict__ Wf,
                                                  const void* __restrict__ att_src,
                                                  const void* __restrict__ att_dst,
                                                  int* __restrict__ flag,
                                                  short* __restrict__ W1t,
                                                  short* __restrict__ Wspt,
                                                  short* __restrict__ Wft,
                                                  short* __restrict__ Wat) {
    const int tid = threadIdx.x;
    if (blockIdx.x < BIN_BLOCKS) {
        __shared__ int cnt[NPART];
        const int b = blockIdx.x;
        if (tid < NPART) cnt[tid] = 0;
        __syncthreads();
        const int e0 = b * 2048;
        #pragma unroll
        for (int t = 0; t < 8; ++t) {
            int e = e0 + t * 256 + tid;
            int s = src[e], d = dst[e];
            int p = d / PART_SZ;
            int dl = d - p * PART_SZ;
            int r = atomicAdd(&cnt[p], 1);
            if (r < SEG_CAP)
                pbuf[((size_t)p * BIN_BLOCKS + b) * SEG_CAP + r] =
                    ((unsigned)s << 16) | (unsigned)dl;
        }
        __syncthreads();
        if (tid < NPART) bcnt[tid * BIN_BLOCKS + b] = min(cnt[tid], SEG_CAP);
        return;
    }
    if (blockIdx.x < BIN_BLOCKS + PREP_BLOCKS) {
        // self-probe dtype (R5-validated): 256-sample exponent test on X
        unsigned ex = (((const unsigned short*)X)[2 * tid] >> 7) & 0xFF;
        int c = __syncthreads_count(ex >= 110 && ex <= 135);
        const int f32 = (c < 128) ? 1 : 0;
        int idx = (blockIdx.x - BIN_BLOCKS) * 256 + tid;
        if (idx < 8192) {
            int n = idx >> 7, k = idx & 127;
            W1t[idx] = f2bs(ldin(W1, (size_t)k * 64 + n, f32));
        } else if (idx < 20480) {
            int j = idx - 8192;
            int col = j / 192;
            int rem = j - col * 192;           // rem = h*64 + kk
            int hh = rem >> 6, kk = rem & 63;
            Wspt[j] = f2bs(ldin(Wsrc, (size_t)kk * 192 + hh * 64 + col, f32) * (1.0f / 3.0f));
        } else if (idx < 28672) {
            int j = idx - 20480;
            int n = j >> 7, k = j & 127;
            Wft[j] = f2bs(ldin(Wf, (size_t)k * 64 + n, f32));
        } else if (idx < 29696) {
            int j = idx - 28672;
            int n = j >> 6, k = j & 63;
            float v = 0.f;
            if (n < 3) {
                for (int c2 = 0; c2 < 64; ++c2)
                    v += ldin(Wsrc, (size_t)k * 192 + n * 64 + c2, f32) * ldin(att_src, n * 64 + c2, f32);
            } else if (n < 6) {
                for (int c2 = 0; c2 < 64; ++c2)
                    v += ldin(Wdst, (size_t)k * 192 + (n - 3) * 64 + c2, f32) * ldin(att_dst, (n - 3) * 64 + c2, f32);
            }
            Wat[j] = f2bs(v);
        }
        return;
    }
    // detect block: write the global flag consumed by downstream kernels
    __shared__ int cntp;
    if (tid == 0) cntp = 0;
    __syncthreads();
    int local = 0;
    const unsigned short* Xu = (const unsigned short*)X;
    for (int i = tid * 2; i < 8192; i += 512) {
        unsigned e = (Xu[i] >> 7) & 0xFF;
        if (e >= 110 && e <= 135) local++;
    }
    atomicAdd(&cntp, local);
    __syncthreads();
    if (tid == 0) *flag = (cntp < 2048) ? 1 : 0;  // 1 = fp32, 0 = bf16
}

// ---------- pass B: LDS counting scatter (256 blocks, zero global atomics) || k1 (800 blocks).
// Scatter block p (200 nodes) scans its 400 segments slot-parallel (56 wave-iters),
// buckets src u16 entries by dst with LDS counters, writes cursor coalesced.
// 4x the parallelism of the R9 64-block variant (which strangled at 11% occupancy).
__global__ __launch_bounds__(256) void k_scatter_k1(const unsigned* __restrict__ pbuf,
                                                    const int* __restrict__ bcnt,
                                                    int* __restrict__ cursor,
                                                    unsigned short* __restrict__ bucket,
                                                    const void* __restrict__ X,
                                                    const short* __restrict__ W1t,
                                                    const short* __restrict__ Wat,
                                                    const void* __restrict__ b1,
                                                    const int* __restrict__ flagp,
                                                    bf16* __restrict__ h_bf,
                                                    unsigned char* __restrict__ h8,
                                                    float* __restrict__ a_src4,
                                                    float* __restrict__ a_dst4) {
    __shared__ short hs[64 * 72];       // k1 tile
    __shared__ int cnt2[PART_SZ];       // scatter branch: per-node counters (800B)
    __shared__ int bc[BIN_BLOCKS];      // scatter branch: segment counts (1.6KB)
    const int tid = threadIdx.x;
    if (blockIdx.x < SC_BLOCKS) {
        const int p = blockIdx.x;
        const int nbase = p * PART_SZ;
        for (int i = tid; i < PART_SZ; i += 256) cnt2[i] = 0;
        for (int i = tid; i < BIN_BLOCKS; i += 256) bc[i] = bcnt[p * BIN_BLOCKS + i];
        __syncthreads();
        const unsigned* pb = pbuf + (size_t)p * BIN_BLOCKS * SEG_CAP;
        for (int i = tid; i < BIN_BLOCKS * SEG_CAP; i += 256) {
            int b = (unsigned)i / SEG_CAP;
            int r = i - b * SEG_CAP;
            if (r < bc[b]) {
                unsigned pk = pb[i];
                int dl = (int)(pk & 0xFFFFu);
                int pos = atomicAdd(&cnt2[dl], 1);
                if (pos < CAP) bucket[(size_t)(nbase + dl) * CAP + pos] = (unsigned short)(pk >> 16);
            }
        }
        __syncthreads();
        for (int i = tid; i < PART_SZ; i += 256) cursor[nbase + i] = cnt2[i];
        return;
    }
    // ----- k1 branch -----
    const int f32 = *flagp;
    const int w    = tid >> 6;
    const int lane = tid & 63;
    const int lm   = lane & 15;
    const int q    = lane >> 4;
    const int row0 = (blockIdx.x - SC_BLOCKS) * 64;

    const float bias = ldin(b1, w * 16 + lm, f32);
    for (int mt = 0; mt < 4; ++mt) {
        f32x4 acc = {0.f, 0.f, 0.f, 0.f};
        #pragma unroll
        for (int kc = 0; kc < 4; ++kc) {
            bf16x8 a = ld8(X, (size_t)(row0 + mt * 16 + lm) * 128 + kc * 32 + q * 8, f32);
            bf16x8 b = *((const bf16x8*)(W1t + (size_t)(w * 16 + lm) * 128 + kc * 32 + q * 8));
            acc = __builtin_amdgcn_mfma_f32_16x16x32_bf16(a, b, acc, 0, 0, 0);
        }
        #pragma unroll
        for (int r = 0; r < 4; ++r) {
            int row = mt * 16 + q * 4 + r;
            float v = leaky(acc[r] + bias, 0.01f);
            short hv = f2bs(v);
            hs[row * 72 + w * 16 + lm] = hv;
            h_bf[(size_t)(row0 + row) * 64 + w * 16 + lm] = __ushort_as_bfloat16((unsigned short)hv);
            h8[(size_t)(row0 + row) * 64 + w * 16 + lm] =
                (unsigned char)__builtin_amdgcn_cvt_pk_fp8_f32(v, 0.f, 0, false);
        }
    }
    __syncthreads();
    {   // stage2: attention-logit projection, wave w owns row-tile mt=w
        const int mt = w;
        bf16x8 a0  = *((const bf16x8*)(hs + (mt * 16 + lm) * 72 + q * 8));
        bf16x8 a1  = *((const bf16x8*)(hs + (mt * 16 + lm) * 72 + 32 + q * 8));
        bf16x8 b0  = *((const bf16x8*)(Wat + (size_t)lm * 64 + q * 8));
        bf16x8 b1v = *((const bf16x8*)(Wat + (size_t)lm * 64 + 32 + q * 8));
        f32x4 acca = {0.f, 0.f, 0.f, 0.f};
        acca = __builtin_amdgcn_mfma_f32_16x16x32_bf16(a0, b0, acca, 0, 0, 0);
        acca = __builtin_amdgcn_mfma_f32_16x16x32_bf16(a1, b1v, acca, 0, 0, 0);
        if (lm < 6) {
            #pragma unroll
            for (int r = 0; r < 4; ++r) {
                int row = row0 + mt * 16 + q * 4 + r;
                if (lm < 3) a_src4[(size_t)row * 4 + lm] = acca[r];
                else        a_dst4[(size_t)row * 4 + (lm - 3)] = acca[r];
            }
        }
    }
}

// ---------- edge aggregation (R6-proven): wave per dst node; fp8 h gather (64B/edge).
__global__ __launch_bounds__(256) void edge_kernel(const unsigned short* __restrict__ bucket,
                                                   const int* __restrict__ cursor,
                                                   const float* __restrict__ a_src4,
                                                   const float* __restrict__ a_dst4,
                                                   const unsigned char* __restrict__ h8,
                                                   float4* __restrict__ dstinfo,
                                                   bf16* __restrict__ wagg) {
    const int lane = threadIdx.x & 63;
    const int w = threadIdx.x >> 6;
    const int n = blockIdx.x * 4 + w;
    const int dg = min(cursor[n], CAP);
    const float4 ad = ((const float4*)a_dst4)[n];
    __shared__ float4 buf[4][64];
    float den0 = 0.f, den1 = 0.f, den2 = 0.f;   // producer-side partials
    float acc0 = 0.f, acc1 = 0.f, acc2 = 0.f;
    for (int c0 = 0; c0 < dg; c0 += 64) {
        int cnt = min(64, dg - c0);
        if (lane < cnt) {
            int s = bucket[(size_t)n * CAP + c0 + lane];
            const float4 as = ((const float4*)a_src4)[s];
            float e0 = __expf(leaky(as.x + ad.x, 0.2f));
            float e1 = __expf(leaky(as.y + ad.y, 0.2f));
            float e2 = __expf(leaky(as.z + ad.z, 0.2f));
            den0 += e0; den1 += e1; den2 += e2;
            buf[w][lane] = make_float4(e0, e1, e2, __int_as_float(s));
        }
        asm volatile("s_waitcnt lgkmcnt(0)" ::: "memory");
        int j = 0;
        for (; j + 8 <= cnt; j += 8) {
            float4 r[8]; int hv[8];
            #pragma unroll
            for (int u = 0; u < 8; ++u) r[u] = buf[w][j + u];
            #pragma unroll
            for (int u = 0; u < 8; ++u)
                hv[u] = (int)h8[(((unsigned)__float_as_int(r[u].w)) << 6) | (unsigned)lane];
            #pragma unroll
            for (int u = 0; u < 8; ++u) {
                float f = __builtin_amdgcn_cvt_f32_fp8(hv[u], 0);
                acc0 += r[u].x * f; acc1 += r[u].y * f; acc2 += r[u].z * f;
            }
        }
        for (; j < cnt; ++j) {
            float4 r = buf[w][j];
            int hvv = (int)h8[(((unsigned)__float_as_int(r.w)) << 6) | (unsigned)lane];
            float f = __builtin_amdgcn_cvt_f32_fp8(hvv, 0);
            acc0 += r.x * f; acc1 += r.y * f; acc2 += r.z * f;
        }
    }
    #pragma unroll
    for (int off = 32; off >= 1; off >>= 1) {
        den0 += __shfl_xor(den0, off);
        den1 += __shfl_xor(den1, off);
        den2 += __shfl_xor(den2, off);
    }
    float inv0 = den0 > 0.f ? 1.f / den0 : 0.f;
    float inv1 = den1 > 0.f ? 1.f / den1 : 0.f;
    float inv2 = den2 > 0.f ? 1.f / den2 : 0.f;
    size_t wb = (size_t)n * 192;
    wagg[wb + lane]       = f2b(acc0 * inv0);
    wagg[wb + 64 + lane]  = f2b(acc1 * inv1);
    wagg[wb + 128 + lane] = f2b(acc2 * inv2);
    if (lane == 0) {
        dstinfo[(size_t)n * 2 + 0] = make_float4(ad.x, ad.y, ad.z, 0.f);
        dstinfo[(size_t)n * 2 + 1] = make_float4(inv0, inv1, inv2, 0.f);
    }
}

// ---------- fused attn (edge-order, blocks 0..3199) + g3 (blocks 3200..3999) with pool fold.
// (R6-proven form: psum/done zeroed by host-side memset each launch.)
__global__ __launch_bounds__(256) void attn_g3_kernel(const int* __restrict__ src,
                                                      const int* __restrict__ dst,
                                                      const float* __restrict__ a_src4,
                                                      const float4* __restrict__ dstinfo,
                                                      const bf16* __restrict__ h_bf,
                                                      const bf16* __restrict__ wagg,
                                                      const short* __restrict__ Wspt,
                                                      const short* __restrict__ Wft,
                                                      const void* __restrict__ gat_bias,
                                                      const void* __restrict__ bfv,
                                                      const int* __restrict__ flagp,
                                                      const int* __restrict__ gptr,
                                                      float* __restrict__ psum,
                                                      int* __restrict__ done,
                                                      void* __restrict__ d_out) {
    const int f32 = *flagp;
    __shared__ short cs[64 * 136];           // g3 branch only
    __shared__ int sptr[N_GRAPHS + 1];
    __shared__ int rowg_s[64];
    __shared__ int readyg[64];
    __shared__ int nready;
    if (blockIdx.x < N_EDGES / 256) {
        int e = blockIdx.x * 256 + threadIdx.x;
        int s = src[e], d = dst[e];
        const float4 as = ((const float4*)a_src4)[s];
        const float4 ad = dstinfo[(size_t)d * 2 + 0];
        const float4 cv = dstinfo[(size_t)d * 2 + 1];
        float a0 = __expf(leaky(as.x + ad.x, 0.2f)) * cv.x;
        float a1 = __expf(leaky(as.y + ad.y, 0.2f)) * cv.y;
        float a2 = __expf(leaky(as.z + ad.z, 0.2f)) * cv.z;
        size_t o = (size_t)N_GRAPHS * DIM_OUT + (size_t)e * 3;
        if (f32) {
            float* p = (float*)d_out;
            p[o] = a0; p[o + 1] = a1; p[o + 2] = a2;
        } else {
            bf16* p = (bf16*)d_out;
            p[o] = f2b(a0); p[o + 1] = f2b(a1); p[o + 2] = f2b(a2);
        }
        return;
    }
    const int bid  = blockIdx.x - N_EDGES / 256;
    const int tid  = threadIdx.x;
    const int w    = tid >> 6;
    const int lane = tid & 63;
    const int lm   = lane & 15;
    const int q    = lane >> 4;
    const int row0 = bid * 64;
    if (tid <= N_GRAPHS) sptr[tid] = gptr[tid];
    if (tid == 0) nready = 0;
    __syncthreads();
    if (tid < 64) {   // row -> graph (binary search; general ptr)
        int row = row0 + tid;
        int lo2 = 0, hi2 = N_GRAPHS;
        while (hi2 - lo2 > 1) { int mid = (lo2 + hi2) >> 1; if (sptr[mid] <= row) lo2 = mid; else hi2 = mid; }
        rowg_s[tid] = lo2;
    }
    // cat[:, 0:64] = leaky(h)
    for (int idx = tid; idx < 64 * 64; idx += 256) {
        int r = idx >> 6, k = idx & 63;
        cs[r * 136 + k] = f2bs(leaky(b2f(h_bf[(size_t)(row0 + r) * 64 + k]), 0.01f));
    }
    // cat[:, 64:128] = leaky(mean_h(wagg_h @ Wsrc_h) + gat_bias)
    {
        const int col = w * 16 + lm;
        const float gb = ldin(gat_bias, col, f32);
        for (int mt = 0; mt < 4; ++mt) {
            f32x4 acc = {0.f, 0.f, 0.f, 0.f};
            #pragma unroll
            for (int kc = 0; kc < 6; ++kc) {
                bf16x8 a = *((const bf16x8*)((const short*)wagg + (size_t)(row0 + mt * 16 + lm) * 192 + kc * 32 + q * 8));
                bf16x8 b = *((const bf16x8*)(Wspt + (size_t)col * 192 + kc * 32 + q * 8));
                acc = __builtin_amdgcn_mfma_f32_16x16x32_bf16(a, b, acc, 0, 0, 0);
            }
            #pragma unroll
            for (int r = 0; r < 4; ++r) {
                int row = mt * 16 + q * 4 + r;
                cs[row * 136 + 64 + col] = f2bs(leaky(acc[r] + gb, 0.01f));
            }
        }
    }
    __syncthreads();
    // final GEMM: y = cat @ Wf + bf, reduced straight into per-graph psum (no y write)
    {
        const int col = w * 16 + lm;
        const float bias = ldin(bfv, col, f32);
        int curg = -1; float runsum = 0.f;
        for (int mt = 0; mt < 4; ++mt) {
            f32x4 acc = {0.f, 0.f, 0.f, 0.f};
            #pragma unroll
            for (int kc = 0; kc < 4; ++kc) {
                bf16x8 a = *((const bf16x8*)(cs + (mt * 16 + lm) * 136 + kc * 32 + q * 8));
                bf16x8 b = *((const bf16x8*)(Wft + (size_t)col * 128 + kc * 32 + q * 8));
                acc = __builtin_amdgcn_mfma_f32_16x16x32_bf16(a, b, acc, 0, 0, 0);
            }
            #pragma unroll
            for (int r = 0; r < 4; ++r) {
                int lrow = mt * 16 + q * 4 + r;
                float v = acc[r] + bias;
                int g = rowg_s[lrow];
                if (g != curg) {
                    if (curg >= 0) atomicAdd(&psum[curg * 64 + col], runsum);
                    curg = g; runsum = 0.f;
                }
                runsum += v;
            }
        }
        if (curg >= 0) atomicAdd(&psum[curg * 64 + col], runsum);
    }
    __syncthreads();   // barrier drains vmcnt -> this block's psum adds are at the coherence point
    if (tid == 0) {
        int g0 = rowg_s[0], g1 = rowg_s[63];
        int nr = 0;
        for (int g = g0; g <= g1; ++g) {
            int lo = sptr[g], hi = sptr[g + 1];
            if (hi <= lo) continue;                       // empty graph
            int expected = (hi - 1) / 64 - lo / 64 + 1;   // tiles overlapping graph g
            int old = atomicAdd(&done[g], 1);
            if (old == expected - 1) readyg[nr++] = g;    // this block is the last tile of g
        }
        nready = nr;
    }
    __syncthreads();
    for (int i = 0; i < nready; ++i) {
        int g = readyg[i];
        if (tid < 64) {
            float s = atomicAdd(&psum[g * 64 + tid], 0.0f);    // coherent read at LLC
            float v = s / (float)(sptr[g + 1] - sptr[g]);
            if (f32) ((float*)d_out)[g * DIM_OUT + tid] = v;
            else     ((bf16*)d_out)[g * DIM_OUT + tid]  = f2b(v);
        }
    }
}

extern "C" void kernel_launch(void* const* d_in, const int* in_sizes, int n_in,
                              void* d_out, int out_size, void* d_ws, size_t ws_size,
                              hipStream_t stream) {
    const void* X        = d_in[0];
    const void* W1       = d_in[1];
    const void* b1       = d_in[2];
    const void* Wsrc     = d_in[3];
    const void* Wdst     = d_in[4];
    const void* att_src  = d_in[5];
    const void* att_dst  = d_in[6];
    const void* gat_bias = d_in[7];
    const void* Wf       = d_in[8];
    const void* bfv      = d_in[9];
    const int*  ei       = (const int*)d_in[10];
    const int*  ptr      = (const int*)d_in[11];
    const int*  src  = ei;
    const int*  dstp = ei + N_EDGES;

    char* ws = (char*)d_ws;
    size_t off_b = 0;
    auto alloc = [&](size_t bytes) -> char* {
        char* p = ws + off_b;
        off_b += (bytes + 255) & ~(size_t)255;
        return p;
    };
    int*     flag    = (int*)    alloc(256);
    short*   W1t     = (short*)  alloc(8192 * 2);
    short*   Wspt    = (short*)  alloc(12288 * 2);
    short*   Wft     = (short*)  alloc(8192 * 2);
    short*   Wat     = (short*)  alloc(1024 * 2);
    bf16*    h_bf    = (bf16*)   alloc((size_t)N_NODES * 64 * 2);
    unsigned char* h8 = (unsigned char*)alloc((size_t)N_NODES * 64);
    float*   a_src4  = (float*)  alloc((size_t)N_NODES * 16);
    float*   a_dst4  = (float*)  alloc((size_t)N_NODES * 16);
    float4*  dstinfo = (float4*) alloc((size_t)N_NODES * 2 * 16);
    bf16*    wagg    = (bf16*)   alloc((size_t)N_NODES * 192 * 2);
    // zeroed region (one small memset): psum(16KB) + done(256B)
    float*   psum    = (float*)  alloc((size_t)N_GRAPHS * 64 * 4);
    int*     done    = (int*)    alloc(256);
    int*     bcnt    = (int*)    alloc((size_t)NPART * BIN_BLOCKS * 4);  // fully rewritten each replay
    int*     cursor  = (int*)    alloc((size_t)N_NODES * 4);             // fully rewritten each replay
    unsigned short* bucket = (unsigned short*)alloc((size_t)N_NODES * CAP * 2);  // 9.8MB
    unsigned* pbuf   = (unsigned*)wagg;    // alias: pbuf (14.7MB) dead before edge_kernel writes wagg
    if (off_b > ws_size) return;

    hipMemsetAsync(psum, 0, (size_t)N_GRAPHS * 64 * 4 + 256, stream);   // psum + done (adjacent)
    hipLaunchKernelGGL(k_bin_prep, dim3(BIN_BLOCKS + PREP_BLOCKS + 1), dim3(256), 0, stream,
                       src, dstp, pbuf, bcnt,
                       X, W1, Wsrc, Wdst, Wf, att_src, att_dst, flag, W1t, Wspt, Wft, Wat);
    hipLaunchKernelGGL(k_scatter_k1, dim3(SC_BLOCKS + K1_BLOCKS), dim3(256), 0, stream,
                       pbuf, bcnt, cursor, bucket,
                       X, W1t, Wat, b1, flag, h_bf, h8, a_src4, a_dst4);
    hipLaunchKernelGGL(edge_kernel, dim3(N_NODES / 4), dim3(256), 0, stream,
                       bucket, cursor, a_src4, a_dst4, h8, dstinfo, wagg);
    hipLaunchKernelGGL(attn_g3_kernel, dim3(N_EDGES / 256 + N_NODES / 64), dim3(256), 0, stream,
                       src, dstp, a_src4, dstinfo, h_bf, wagg, Wspt, Wft,
                       gat_bias, bfv, flag, ptr, psum, done, d_out);
}

// Round 12
// 203.303 us; speedup vs baseline: 1.1408x; 1.0345x over previous
//
#include <hip/hip_runtime.h>
#include <hip/hip_bf16.h>

#define N_NODES   51200
#define N_GRAPHS  64
#define N_EDGES   819200
#define DIM_IN    128
#define DH        64
#define HEADS     3
#define DIM_OUT   64
#define CAP       96       // bucket capacity per dst node (R6-proven); P(deg>96) ~ 0
#define NPART     512      // scatter partitions: 100 nodes each (pure node-space split)
#define PART_SZ   100
#define PBUF_CAP  2048     // per-partition compacted cap (mean 1600, sd 40: +11 sigma)
#define BIN_BLOCKS  400    // N_EDGES / 2048
#define PREP_BLOCKS 116    // 29696 weight-prep elements / 256
#define SC_BLOCKS   NPART  // 512 counting-scatter blocks
#define K1_BLOCKS   (N_NODES / 64)   // 800

typedef __hip_bfloat16 bf16;
typedef short bf16x8 __attribute__((ext_vector_type(8)));
typedef float f32x4  __attribute__((ext_vector_type(4)));

__device__ __forceinline__ float b2f(bf16 x) { return __bfloat162float(x); }
__device__ __forceinline__ bf16  f2b(float x) { return __float2bfloat16(x); }
__device__ __forceinline__ short f2bs(float x) { return (short)__bfloat16_as_ushort(f2b(x)); }
__device__ __forceinline__ float leaky(float x, float s) { return x >= 0.f ? x : s * x; }
// flag-branched input load: f32==1 -> data is float32 (the ACTIVE path per earlier bisect)
__device__ __forceinline__ float ldin(const void* p, size_t i, int f32) {
    return f32 ? ((const float*)p)[i] : b2f(((const bf16*)p)[i]);
}
__device__ __forceinline__ bf16x8 ld8(const void* p, size_t i, int f32) {
    if (!f32) return *((const bf16x8*)((const short*)p + i));
    const float* f = (const float*)p + i;
    bf16x8 r;
    #pragma unroll
    for (int j = 0; j < 8; ++j) r[j] = f2bs(f[j]);
    return r;
}

// ---------- pass A: COMPACTED binning (atomic range reservation; R3-proven pattern at
// 512 partitions) + weight prep + detect. pbuf[p][0..pcur[p]) u32 = (src<<16)|dlocal, dense.
__global__ __launch_bounds__(256) void k_bin_prep(const int* __restrict__ src,
                                                  const int* __restrict__ dst,
                                                  int* __restrict__ pcur,
                                                  unsigned* __restrict__ pbuf,
                                                  const void* __restrict__ X,
                                                  const void* __restrict__ W1,
                                                  const void* __restrict__ Wsrc,
                                                  const void* __restrict__ Wdst,
                                                  const void* __restrict__ Wf,
                                                  const void* __restrict__ att_src,
                                                  const void* __restrict__ att_dst,
                                                  int* __restrict__ flag,
                                                  short* __restrict__ W1t,
                                                  short* __restrict__ Wspt,
                                                  short* __restrict__ Wft,
                                                  short* __restrict__ Wat) {
    const int tid = threadIdx.x;
    if (blockIdx.x < BIN_BLOCKS) {
        __shared__ int cnt[NPART];
        __shared__ int base[NPART];
        cnt[tid] = 0; cnt[tid + 256] = 0;
        __syncthreads();
        const int e0 = blockIdx.x * 2048;
        unsigned pk[8]; int pp[8]; int rr[8];
        #pragma unroll
        for (int t = 0; t < 8; ++t) {
            int e = e0 + t * 256 + tid;
            int s = src[e], d = dst[e];
            int p = d / PART_SZ;
            pk[t] = ((unsigned)s << 16) | (unsigned)(d - p * PART_SZ);
            pp[t] = p;
            rr[t] = atomicAdd(&cnt[p], 1);
        }
        __syncthreads();
        base[tid]       = atomicAdd(&pcur[tid],       cnt[tid]);
        base[tid + 256] = atomicAdd(&pcur[tid + 256], cnt[tid + 256]);
        __syncthreads();
        #pragma unroll
        for (int t = 0; t < 8; ++t) {
            int o = base[pp[t]] + rr[t];
            if (o < PBUF_CAP) pbuf[(size_t)pp[t] * PBUF_CAP + o] = pk[t];
        }
        return;
    }
    if (blockIdx.x < BIN_BLOCKS + PREP_BLOCKS) {
        // self-probe dtype (R5-validated): 256-sample exponent test on X
        unsigned ex = (((const unsigned short*)X)[2 * tid] >> 7) & 0xFF;
        int c = __syncthreads_count(ex >= 110 && ex <= 135);
        const int f32 = (c < 128) ? 1 : 0;
        int idx = (blockIdx.x - BIN_BLOCKS) * 256 + tid;
        if (idx < 8192) {
            int n = idx >> 7, k = idx & 127;
            W1t[idx] = f2bs(ldin(W1, (size_t)k * 64 + n, f32));
        } else if (idx < 20480) {
            int j = idx - 8192;
            int col = j / 192;
            int rem = j - col * 192;           // rem = h*64 + kk
            int hh = rem >> 6, kk = rem & 63;
            Wspt[j] = f2bs(ldin(Wsrc, (size_t)kk * 192 + hh * 64 + col, f32) * (1.0f / 3.0f));
        } else if (idx < 28672) {
            int j = idx - 20480;
            int n = j >> 7, k = j & 127;
            Wft[j] = f2bs(ldin(Wf, (size_t)k * 64 + n, f32));
        } else if (idx < 29696) {
            int j = idx - 28672;
            int n = j >> 6, k = j & 63;
            float v = 0.f;
            if (n < 3) {
                for (int c2 = 0; c2 < 64; ++c2)
                    v += ldin(Wsrc, (size_t)k * 192 + n * 64 + c2, f32) * ldin(att_src, n * 64 + c2, f32);
            } else if (n < 6) {
                for (int c2 = 0; c2 < 64; ++c2)
                    v += ldin(Wdst, (size_t)k * 192 + (n - 3) * 64 + c2, f32) * ldin(att_dst, (n - 3) * 64 + c2, f32);
            }
            Wat[j] = f2bs(v);
        }
        return;
    }
    // detect block: write the global flag consumed by downstream kernels
    __shared__ int cntp;
    if (tid == 0) cntp = 0;
    __syncthreads();
    int local = 0;
    const unsigned short* Xu = (const unsigned short*)X;
    for (int i = tid * 2; i < 8192; i += 512) {
        unsigned e = (Xu[i] >> 7) & 0xFF;
        if (e >= 110 && e <= 135) local++;
    }
    atomicAdd(&cntp, local);
    __syncthreads();
    if (tid == 0) *flag = (cntp < 2048) ? 1 : 0;  // 1 = fp32, 0 = bf16
}

// ---------- pass B: LDS counting scatter (512 blocks, compacted reads) || k1 (800 blocks).
// Scatter block p (100 nodes) reads its EXACT contiguous run (~1600 u32, 6 wave-iters,
// no empty-slot checks), buckets src u16 entries by dst with LDS counters, writes
// cursor coalesced. Compaction cuts scatter reads 14.7MB -> 3.3MB vs R11.
__global__ __launch_bounds__(256) void k_scatter_k1(const unsigned* __restrict__ pbuf,
                                                    const int* __restrict__ pcur,
                                                    int* __restrict__ cursor,
                                                    unsigned short* __restrict__ bucket,
                                                    const void* __restrict__ X,
                                                    const short* __restrict__ W1t,
                                                    const short* __restrict__ Wat,
                                                    const void* __restrict__ b1,
                                                    const int* __restrict__ flagp,
                                                    bf16* __restrict__ h_bf,
                                                    unsigned char* __restrict__ h8,
                                                    float* __restrict__ a_src4,
                                                    float* __restrict__ a_dst4) {
    __shared__ short hs[64 * 72];       // k1 tile
    __shared__ int cnt2[PART_SZ];       // scatter branch: per-node counters (400B)
    const int tid = threadIdx.x;
    if (blockIdx.x < SC_BLOCKS) {
        const int p = blockIdx.x;
        const int nbase = p * PART_SZ;
        for (int i = tid; i < PART_SZ; i += 256) cnt2[i] = 0;
        __syncthreads();
        const int pc = min(pcur[p], PBUF_CAP);
        const unsigned* pb = pbuf + (size_t)p * PBUF_CAP;
        for (int i = tid; i < pc; i += 256) {
            unsigned pk = pb[i];
            int dl = (int)(pk & 0xFFFFu);
            int pos = atomicAdd(&cnt2[dl], 1);
            if (pos < CAP) bucket[(size_t)(nbase + dl) * CAP + pos] = (unsigned short)(pk >> 16);
        }
        __syncthreads();
        for (int i = tid; i < PART_SZ; i += 256) cursor[nbase + i] = cnt2[i];
        return;
    }
    // ----- k1 branch -----
    const int f32 = *flagp;
    const int w    = tid >> 6;
    const int lane = tid & 63;
    const int lm   = lane & 15;
    const int q    = lane >> 4;
    const int row0 = (blockIdx.x - SC_BLOCKS) * 64;

    const float bias = ldin(b1, w * 16 + lm, f32);
    for (int mt = 0; mt < 4; ++mt) {
        f32x4 acc = {0.f, 0.f, 0.f, 0.f};
        #pragma unroll
        for (int kc = 0; kc < 4; ++kc) {
            bf16x8 a = ld8(X, (size_t)(row0 + mt * 16 + lm) * 128 + kc * 32 + q * 8, f32);
            bf16x8 b = *((const bf16x8*)(W1t + (size_t)(w * 16 + lm) * 128 + kc * 32 + q * 8));
            acc = __builtin_amdgcn_mfma_f32_16x16x32_bf16(a, b, acc, 0, 0, 0);
        }
        #pragma unroll
        for (int r = 0; r < 4; ++r) {
            int row = mt * 16 + q * 4 + r;
            float v = leaky(acc[r] + bias, 0.01f);
            short hv = f2bs(v);
            hs[row * 72 + w * 16 + lm] = hv;
            h_bf[(size_t)(row0 + row) * 64 + w * 16 + lm] = __ushort_as_bfloat16((unsigned short)hv);
            h8[(size_t)(row0 + row) * 64 + w * 16 + lm] =
                (unsigned char)__builtin_amdgcn_cvt_pk_fp8_f32(v, 0.f, 0, false);
        }
    }
    __syncthreads();
    {   // stage2: attention-logit projection, wave w owns row-tile mt=w
        const int mt = w;
        bf16x8 a0  = *((const bf16x8*)(hs + (mt * 16 + lm) * 72 + q * 8));
        bf16x8 a1  = *((const bf16x8*)(hs + (mt * 16 + lm) * 72 + 32 + q * 8));
        bf16x8 b0  = *((const bf16x8*)(Wat + (size_t)lm * 64 + q * 8));
        bf16x8 b1v = *((const bf16x8*)(Wat + (size_t)lm * 64 + 32 + q * 8));
        f32x4 acca = {0.f, 0.f, 0.f, 0.f};
        acca = __builtin_amdgcn_mfma_f32_16x16x32_bf16(a0, b0, acca, 0, 0, 0);
        acca = __builtin_amdgcn_mfma_f32_16x16x32_bf16(a1, b1v, acca, 0, 0, 0);
        if (lm < 6) {
            #pragma unroll
            for (int r = 0; r < 4; ++r) {
                int row = row0 + mt * 16 + q * 4 + r;
                if (lm < 3) a_src4[(size_t)row * 4 + lm] = acca[r];
                else        a_dst4[(size_t)row * 4 + (lm - 3)] = acca[r];
            }
        }
    }
}

// ---------- edge aggregation (R6-proven): wave per dst node; fp8 h gather (64B/edge).
__global__ __launch_bounds__(256) void edge_kernel(const unsigned short* __restrict__ bucket,
                                                   const int* __restrict__ cursor,
                                                   const float* __restrict__ a_src4,
                                                   const float* __restrict__ a_dst4,
                                                   const unsigned char* __restrict__ h8,
                                                   float4* __restrict__ dstinfo,
                                                   bf16* __restrict__ wagg) {
    const int lane = threadIdx.x & 63;
    const int w = threadIdx.x >> 6;
    const int n = blockIdx.x * 4 + w;
    const int dg = min(cursor[n], CAP);
    const float4 ad = ((const float4*)a_dst4)[n];
    __shared__ float4 buf[4][64];
    float den0 = 0.f, den1 = 0.f, den2 = 0.f;   // producer-side partials
    float acc0 = 0.f, acc1 = 0.f, acc2 = 0.f;
    for (int c0 = 0; c0 < dg; c0 += 64) {
        int cnt = min(64, dg - c0);
        if (lane < cnt) {
            int s = bucket[(size_t)n * CAP + c0 + lane];
            const float4 as = ((const float4*)a_src4)[s];
            float e0 = __expf(leaky(as.x + ad.x, 0.2f));
            float e1 = __expf(leaky(as.y + ad.y, 0.2f));
            float e2 = __expf(leaky(as.z + ad.z, 0.2f));
            den0 += e0; den1 += e1; den2 += e2;
            buf[w][lane] = make_float4(e0, e1, e2, __int_as_float(s));
        }
        asm volatile("s_waitcnt lgkmcnt(0)" ::: "memory");
        int j = 0;
        for (; j + 8 <= cnt; j += 8) {
            float4 r[8]; int hv[8];
            #pragma unroll
            for (int u = 0; u < 8; ++u) r[u] = buf[w][j + u];
            #pragma unroll
            for (int u = 0; u < 8; ++u)
                hv[u] = (int)h8[(((unsigned)__float_as_int(r[u].w)) << 6) | (unsigned)lane];
            #pragma unroll
            for (int u = 0; u < 8; ++u) {
                float f = __builtin_amdgcn_cvt_f32_fp8(hv[u], 0);
                acc0 += r[u].x * f; acc1 += r[u].y * f; acc2 += r[u].z * f;
            }
        }
        for (; j < cnt; ++j) {
            float4 r = buf[w][j];
            int hvv = (int)h8[(((unsigned)__float_as_int(r.w)) << 6) | (unsigned)lane];
            float f = __builtin_amdgcn_cvt_f32_fp8(hvv, 0);
            acc0 += r.x * f; acc1 += r.y * f; acc2 += r.z * f;
        }
    }
    #pragma unroll
    for (int off = 32; off >= 1; off >>= 1) {
        den0 += __shfl_xor(den0, off);
        den1 += __shfl_xor(den1, off);
        den2 += __shfl_xor(den2, off);
    }
    float inv0 = den0 > 0.f ? 1.f / den0 : 0.f;
    float inv1 = den1 > 0.f ? 1.f / den1 : 0.f;
    float inv2 = den2 > 0.f ? 1.f / den2 : 0.f;
    size_t wb = (size_t)n * 192;
    wagg[wb + lane]       = f2b(acc0 * inv0);
    wagg[wb + 64 + lane]  = f2b(acc1 * inv1);
    wagg[wb + 128 + lane] = f2b(acc2 * inv2);
    if (lane == 0) {
        dstinfo[(size_t)n * 2 + 0] = make_float4(ad.x, ad.y, ad.z, 0.f);
        dstinfo[(size_t)n * 2 + 1] = make_float4(inv0, inv1, inv2, 0.f);
    }
}

// ---------- fused attn (edge-order, blocks 0..3199) + g3 (blocks 3200..3999) with pool fold.
// (R6-proven form: psum/done zeroed by host-side memset each launch.)
__global__ __launch_bounds__(256) void attn_g3_kernel(const int* __restrict__ src,
                                                      const int* __restrict__ dst,
                                                      const float* __restrict__ a_src4,
                                                      const float4* __restrict__ dstinfo,
                                                      const bf16* __restrict__ h_bf,
                                                      const bf16* __restrict__ wagg,
                                                      const short* __restrict__ Wspt,
                                                      const short* __restrict__ Wft,
                                                      const void* __restrict__ gat_bias,
                                                      const void* __restrict__ bfv,
                                                      const int* __restrict__ flagp,
                                                      const int* __restrict__ gptr,
                                                      float* __restrict__ psum,
                                                      int* __restrict__ done,
                                                      void* __restrict__ d_out) {
    const int f32 = *flagp;
    __shared__ short cs[64 * 136];           // g3 branch only
    __shared__ int sptr[N_GRAPHS + 1];
    __shared__ int rowg_s[64];
    __shared__ int readyg[64];
    __shared__ int nready;
    if (blockIdx.x < N_EDGES / 256) {
        int e = blockIdx.x * 256 + threadIdx.x;
        int s = src[e], d = dst[e];
        const float4 as = ((const float4*)a_src4)[s];
        const float4 ad = dstinfo[(size_t)d * 2 + 0];
        const float4 cv = dstinfo[(size_t)d * 2 + 1];
        float a0 = __expf(leaky(as.x + ad.x, 0.2f)) * cv.x;
        float a1 = __expf(leaky(as.y + ad.y, 0.2f)) * cv.y;
        float a2 = __expf(leaky(as.z + ad.z, 0.2f)) * cv.z;
        size_t o = (size_t)N_GRAPHS * DIM_OUT + (size_t)e * 3;
        if (f32) {
            float* p = (float*)d_out;
            p[o] = a0; p[o + 1] = a1; p[o + 2] = a2;
        } else {
            bf16* p = (bf16*)d_out;
            p[o] = f2b(a0); p[o + 1] = f2b(a1); p[o + 2] = f2b(a2);
        }
        return;
    }
    const int bid  = blockIdx.x - N_EDGES / 256;
    const int tid  = threadIdx.x;
    const int w    = tid >> 6;
    const int lane = tid & 63;
    const int lm   = lane & 15;
    const int q    = lane >> 4;
    const int row0 = bid * 64;
    if (tid <= N_GRAPHS) sptr[tid] = gptr[tid];
    if (tid == 0) nready = 0;
    __syncthreads();
    if (tid < 64) {   // row -> graph (binary search; general ptr)
        int row = row0 + tid;
        int lo2 = 0, hi2 = N_GRAPHS;
        while (hi2 - lo2 > 1) { int mid = (lo2 + hi2) >> 1; if (sptr[mid] <= row) lo2 = mid; else hi2 = mid; }
        rowg_s[tid] = lo2;
    }
    // cat[:, 0:64] = leaky(h)
    for (int idx = tid; idx < 64 * 64; idx += 256) {
        int r = idx >> 6, k = idx & 63;
        cs[r * 136 + k] = f2bs(leaky(b2f(h_bf[(size_t)(row0 + r) * 64 + k]), 0.01f));
    }
    // cat[:, 64:128] = leaky(mean_h(wagg_h @ Wsrc_h) + gat_bias)
    {
        const int col = w * 16 + lm;
        const float gb = ldin(gat_bias, col, f32);
        for (int mt = 0; mt < 4; ++mt) {
            f32x4 acc = {0.f, 0.f, 0.f, 0.f};
            #pragma unroll
            for (int kc = 0; kc < 6; ++kc) {
                bf16x8 a = *((const bf16x8*)((const short*)wagg + (size_t)(row0 + mt * 16 + lm) * 192 + kc * 32 + q * 8));
                bf16x8 b = *((const bf16x8*)(Wspt + (size_t)col * 192 + kc * 32 + q * 8));
                acc = __builtin_amdgcn_mfma_f32_16x16x32_bf16(a, b, acc, 0, 0, 0);
            }
            #pragma unroll
            for (int r = 0; r < 4; ++r) {
                int row = mt * 16 + q * 4 + r;
                cs[row * 136 + 64 + col] = f2bs(leaky(acc[r] + gb, 0.01f));
            }
        }
    }
    __syncthreads();
    // final GEMM: y = cat @ Wf + bf, reduced straight into per-graph psum (no y write)
    {
        const int col = w * 16 + lm;
        const float bias = ldin(bfv, col, f32);
        int curg = -1; float runsum = 0.f;
        for (int mt = 0; mt < 4; ++mt) {
            f32x4 acc = {0.f, 0.f, 0.f, 0.f};
            #pragma unroll
            for (int kc = 0; kc < 4; ++kc) {
                bf16x8 a = *((const bf16x8*)(cs + (mt * 16 + lm) * 136 + kc * 32 + q * 8));
                bf16x8 b = *((const bf16x8*)(Wft + (size_t)col * 128 + kc * 32 + q * 8));
                acc = __builtin_amdgcn_mfma_f32_16x16x32_bf16(a, b, acc, 0, 0, 0);
            }
            #pragma unroll
            for (int r = 0; r < 4; ++r) {
                int lrow = mt * 16 + q * 4 + r;
                float v = acc[r] + bias;
                int g = rowg_s[lrow];
                if (g != curg) {
                    if (curg >= 0) atomicAdd(&psum[curg * 64 + col], runsum);
                    curg = g; runsum = 0.f;
                }
                runsum += v;
            }
        }
        if (curg >= 0) atomicAdd(&psum[curg * 64 + col], runsum);
    }
    __syncthreads();   // barrier drains vmcnt -> this block's psum adds are at the coherence point
    if (tid == 0) {
        int g0 = rowg_s[0], g1 = rowg_s[63];
        int nr = 0;
        for (int g = g0; g <= g1; ++g) {
            int lo = sptr[g], hi = sptr[g + 1];
            if (hi <= lo) continue;                       // empty graph
            int expected = (hi - 1) / 64 - lo / 64 + 1;   // tiles overlapping graph g
            int old = atomicAdd(&done[g], 1);
            if (old == expected - 1) readyg[nr++] = g;    // this block is the last tile of g
        }
        nready = nr;
    }
    __syncthreads();
    for (int i = 0; i < nready; ++i) {
        int g = readyg[i];
        if (tid < 64) {
            float s = atomicAdd(&psum[g * 64 + tid], 0.0f);    // coherent read at LLC
            float v = s / (float)(sptr[g + 1] - sptr[g]);
            if (f32) ((float*)d_out)[g * DIM_OUT + tid] = v;
            else     ((bf16*)d_out)[g * DIM_OUT + tid]  = f2b(v);
        }
    }
}

extern "C" void kernel_launch(void* const* d_in, const int* in_sizes, int n_in,
                              void* d_out, int out_size, void* d_ws, size_t ws_size,
                              hipStream_t stream) {
    const void* X        = d_in[0];
    const void* W1       = d_in[1];
    const void* b1       = d_in[2];
    const void* Wsrc     = d_in[3];
    const void* Wdst     = d_in[4];
    const void* att_src  = d_in[5];
    const void* att_dst  = d_in[6];
    const void* gat_bias = d_in[7];
    const void* Wf       = d_in[8];
    const void* bfv      = d_in[9];
    const int*  ei       = (const int*)d_in[10];
    const int*  ptr      = (const int*)d_in[11];
    const int*  src  = ei;
    const int*  dstp = ei + N_EDGES;

    char* ws = (char*)d_ws;
    size_t off_b = 0;
    auto alloc = [&](size_t bytes) -> char* {
        char* p = ws + off_b;
        off_b += (bytes + 255) & ~(size_t)255;
        return p;
    };
    int*     flag    = (int*)    alloc(256);
    short*   W1t     = (short*)  alloc(8192 * 2);
    short*   Wspt    = (short*)  alloc(12288 * 2);
    short*   Wft     = (short*)  alloc(8192 * 2);
    short*   Wat     = (short*)  alloc(1024 * 2);
    bf16*    h_bf    = (bf16*)   alloc((size_t)N_NODES * 64 * 2);
    unsigned char* h8 = (unsigned char*)alloc((size_t)N_NODES * 64);
    float*   a_src4  = (float*)  alloc((size_t)N_NODES * 16);
    float*   a_dst4  = (float*)  alloc((size_t)N_NODES * 16);
    float4*  dstinfo = (float4*) alloc((size_t)N_NODES * 2 * 16);
    bf16*    wagg    = (bf16*)   alloc((size_t)N_NODES * 192 * 2);
    // zeroed region (one small memset): psum(16KB) + done(256B) + pcur(2KB)
    float*   psum    = (float*)  alloc((size_t)N_GRAPHS * 64 * 4);
    int*     done    = (int*)    alloc(256);
    int*     pcur    = (int*)    alloc(NPART * 4);
    int*     cursor  = (int*)    alloc((size_t)N_NODES * 4);             // fully rewritten each replay
    unsigned short* bucket = (unsigned short*)alloc((size_t)N_NODES * CAP * 2);  // 9.8MB
    unsigned* pbuf   = (unsigned*)wagg;    // alias: pbuf (4MB compacted) dead before edge_kernel writes wagg
    if (off_b > ws_size) return;

    hipMemsetAsync(psum, 0, (size_t)N_GRAPHS * 64 * 4 + 256 + NPART * 4, stream);  // psum+done+pcur
    hipLaunchKernelGGL(k_bin_prep, dim3(BIN_BLOCKS + PREP_BLOCKS + 1), dim3(256), 0, stream,
                       src, dstp, pcur, pbuf,
                       X, W1, Wsrc, Wdst, Wf, att_src, att_dst, flag, W1t, Wspt, Wft, Wat);
    hipLaunchKernelGGL(k_scatter_k1, dim3(SC_BLOCKS + K1_BLOCKS), dim3(256), 0, stream,
                       pbuf, pcur, cursor, bucket,
                       X, W1t, Wat, b1, flag, h_bf, h8, a_src4, a_dst4);
    hipLaunchKernelGGL(edge_kernel, dim3(N_NODES / 4), dim3(256), 0, stream,
                       bucket, cursor, a_src4, a_dst4, h8, dstinfo, wagg);
    hipLaunchKernelGGL(attn_g3_kernel, dim3(N_EDGES / 256 + N_NODES / 64), dim3(256), 0, stream,
                       src, dstp, a_src4, dstinfo, h_bf, wagg, Wspt, Wft,
                       gat_bias, bfv, flag, ptr, psum, done, d_out);
}